// Round 14
// baseline (116.792 us; speedup 1.0000x reference)
//
#include <hip/hip_runtime.h>
#include <cstdint>

// Problem constants: B=32, T=D=256, rows R = B*T = 8192, K = 256.
#define R_TOT 8192
#define KD    256
#define SLOT  ((size_t)R_TOT * KD)            // bytes per fp8 image (2,097,152)
// ws layout (bytes):  total ~4.8 MB
#define IVN_OFF  0                            // 64 f32: 1/frobenius-norm [ten][j]
#define ICN_OFF  256                          // 2*8192 f32: 1/col-norm [ten][j][s]
#define CSQ_OFF  (ICN_OFF + 65536)            // 8 tc-partials x 2*8192 f32 = 512 KB
#define MATS_OFF (CSQ_OFF + 524288)           // 2 fp8 images (Vq, Aq), swizzled, 4 MB

typedef float f32x4 __attribute__((ext_vector_type(4)));
typedef int   i32x4 __attribute__((ext_vector_type(4)));
typedef int   i32x8 __attribute__((ext_vector_type(8)));   // 32 fp8 = one MX MFMA operand

__device__ __forceinline__ void glds16(const void* g, void* l){
  __builtin_amdgcn_global_load_lds((const __attribute__((address_space(1))) uint32_t*)g,
                                   (__attribute__((address_space(3))) uint32_t*)l, 16, 0, 0);
}

// Image layout (R11-verbatim): plain k-order rows (256 B per image row r), 16B
// chunk c (k in [c*16, c*16+16)) stored at 16B slot c ^ (r & 15). XOR swizzle
// keeps MFMA-layout ds_read_b128 conflict-free (verified R7-R11).
__global__ void cast_ns_k(const float* __restrict__ V, const float* __restrict__ A,
                          unsigned char* __restrict__ mats, float* __restrict__ csq){
  const int tc = blockIdx.x, j = blockIdx.y, ten = blockIdx.z;
  const int tid = threadIdx.x;
  const int g    = tid & 31;                 // d-chunk of 8 floats = 8 fp8 bytes
  const int tsub = tid >> 5;                 // 0..7
  const int c    = g >> 1;                   // 16B chunk index 0..15
  const int half = g & 1;                    // which 8B half of the chunk
  const float* X = (ten ? A : V) + (size_t)j * 65536;
  unsigned char* M = mats + (size_t)ten * SLOT + (size_t)j * 65536;
  float cs[8];
  #pragma unroll
  for (int e = 0; e < 8; ++e) cs[e] = 0.f;
  #pragma unroll
  for (int tt = 0; tt < 4; ++tt){
    const int t = tc * 32 + tt * 8 + tsub;
    const float4 p0 = *(const float4*)(X + t * 256 + g * 8);
    const float4 p1 = *(const float4*)(X + t * 256 + g * 8 + 4);
    cs[0] += p0.x * p0.x; cs[1] += p0.y * p0.y; cs[2] += p0.z * p0.z; cs[3] += p0.w * p0.w;
    cs[4] += p1.x * p1.x; cs[5] += p1.y * p1.y; cs[6] += p1.z * p1.z; cs[7] += p1.w * p1.w;
    int d0 = __builtin_amdgcn_cvt_pk_fp8_f32(p0.x, p0.y, 0, false);
    d0     = __builtin_amdgcn_cvt_pk_fp8_f32(p0.z, p0.w, d0, true);
    int d1 = __builtin_amdgcn_cvt_pk_fp8_f32(p1.x, p1.y, 0, false);
    d1     = __builtin_amdgcn_cvt_pk_fp8_f32(p1.z, p1.w, d1, true);
    int2 o; o.x = d0; o.y = d1;
    *(int2*)(M + (size_t)t * 256 + (((c ^ (t & 15)) << 4) | (half << 3))) = o;
  }
  __shared__ float red[8][256];
  #pragma unroll
  for (int e = 0; e < 8; ++e) red[tsub][g * 8 + e] = cs[e];
  __syncthreads();
  float s = 0.f;
  #pragma unroll
  for (int gg = 0; gg < 8; ++gg) s += red[gg][tid];
  csq[(size_t)((tc * 2 + ten) * 32 + j) * 256 + tid] = s;
}

// Finish norms: sum 8 tc-partials; icn = rsqrt, ivn = rsqrt of row-sum. Grid (32, 2).
__global__ void nreduce_k(const float* __restrict__ csq, float* __restrict__ ivn,
                          float* __restrict__ icn){
  const int j = blockIdx.x, ten = blockIdx.y, s = threadIdx.x;
  float c = 0.f;
  #pragma unroll
  for (int tc = 0; tc < 8; ++tc)
    c += csq[(size_t)((tc * 2 + ten) * 32 + j) * 256 + s];
  icn[ten * 8192 + j * 256 + s] = rsqrtf(c + 1e-18f);
  __shared__ float red[256];
  red[s] = c; __syncthreads();
  for (int off = 128; off > 0; off >>= 1){
    if (s < off) red[s] += red[s + off];
    __syncthreads();
  }
  if (s == 0) ivn[ten * 32 + j] = rsqrtf(red[0] + 1e-18f);
}

// v27 = v26 (counted-vmcnt 2-tile windows, zero mid-loop drains, 16 barriers,
// shared staging 127MB, 4 waves/SIMD) + addressing micro pass:
//  - window loop FULLY UNROLLED -> tile index x compile-time -> the buffer
//    offset ((x&7)<<12) folds into ds_read/glds IMMEDIATE offsets instead of
//    per-tile v_adds;
//  - loop-invariant pointer sums (dbase+ad[t][u], glds src/dst bases)
//    hoisted once.
// Rationale: v13..v26 mapped the full schedule space -- {1,2,4} waves/SIMD x
// {fat,thin} waves x {private,shared} staging x {1,2,4}-tile windows x
// {drained,counted} vmcnt all land 42.5-53us (min = v22/v26 cell). Remaining
// attackable cost from source = per-tile addressing + loop control; this
// removes it without touching the proven schedule/live-set/numerics.
// SPILL DETECTOR: WRITE_SIZE (clean = 8MB; ballooned -> unroll raised
// pressure, revert to v26's rolled loop).
__global__ __launch_bounds__(512, 4) void gemm_both_k(const unsigned char* __restrict__ mats,
                                                      const float* __restrict__ ivn,
                                                      const float* __restrict__ icn,
                                                      float* __restrict__ out){
  // [0,64K): 2 dirs x 8 bufs x 4KB staging; [64K,68K): csc[2][32][16] f32.
  // Epilogue ebuf f32[2][256][20] = 40960 B aliases the staging (post-loop).
  __shared__ __align__(16) char smem[69632];
  const int tid  = threadIdx.x;
  const int lane = tid & 63;
  const int w    = tid >> 6;            // 0..7
  const int dir  = w >> 2;              // waves 0-3 -> dir0; 4-7 -> dir1
  const int sub  = w & 3;               // row-64-group AND staging-chunk index
  const int lm   = lane & 15;
  const int kh   = lane >> 4;           // 0..3 (k-quad per K-half)
  const int s0   = blockIdx.x * 16;     // 16-col tile
  const int rb   = blockIdx.y;          // row-block == batch index i
  const int r0   = rb * 256;
  const int ib   = rb;                  // excluded diagonal j == i

  // dir0: rows Vq (scale 1/|V_i|F), cols Aq (scale 1/colnorm A); dir1 swapped.
  const unsigned char* rowmat = mats + (size_t)dir * SLOT;
  const unsigned char* colmat = mats + (size_t)(1 - dir) * SLOT;
  const float sivn = ivn[dir * 32 + ib] * 1.44269504088896340736f;  // * log2(e)

  char*  dbase = smem + dir * 32768;                  // this dir's 8 x 4KB bufs
  float* cscw  = (float*)(smem + 65536) + dir * 512;  // this dir's csc[32][16]
  const int lo16 = lane * 16;

  // Hoisted glds bases: src = colbase + j*65536 (j runtime), dst = dbase +
  // bufoff (compile-time after unroll).
  const unsigned char* gsrc = colmat + (size_t)s0 * 256 + sub * 1024 + lo16;
  char* gdst = dbase + sub * 1024 + lo16;

  // Stage this wave's 1KB chunk of the dir's 4KB tile for col-tile x.
  auto issue = [&](int x){
    const int j = x + (x >= ib ? 1 : 0);
    glds16(gsrc + (size_t)j * 65536, gdst + ((x & 7) << 12));
  };

  issue(0); issue(1);

  // Block-shared csc table (per dir): csc[j][col] = sivn * icn_col[j*256+s0+col].
  {
    const float* ib2 = icn + (size_t)(1 - dir) * 8192 + s0 + lm;
    #pragma unroll
    for (int jx = 0; jx < 2; ++jx){
      const int j = sub * 8 + jx * 4 + kh;
      cscw[j * 16 + lm] = sivn * ib2[j * 256];
    }
  }

  // A-fragments: this wave's 64 rows (group sub of the 256-row block);
  // K-half t, 16B unit u at slot (t*8 + kh*2 + u) ^ lm. 64 regs, invariant.
  i32x8 afr[4][2];                      // [mi][K-half]
  #pragma unroll
  for (int mi = 0; mi < 4; ++mi){
    const unsigned char* rp = rowmat + (size_t)(r0 + sub * 64 + mi * 16 + lm) * 256;
    #pragma unroll
    for (int t = 0; t < 2; ++t){
      i32x4 lo = *(const i32x4*)(rp + ((((t << 3) | (kh << 1) | 0) ^ lm) << 4));
      i32x4 hi = *(const i32x4*)(rp + ((((t << 3) | (kh << 1) | 1) ^ lm) << 4));
      afr[mi][t] = i32x8{lo.x, lo.y, lo.z, lo.w, hi.x, hi.y, hi.z, hi.w};
    }
  }
  #pragma unroll
  for (int mi = 0; mi < 4; ++mi)
    #pragma unroll
    for (int t = 0; t < 2; ++t)
      asm volatile("" : "+v"(afr[mi][t]));

  issue(2); issue(3); issue(4); issue(5);

  // Hoisted ds_read base pointers: adp[t][u] = dbase + tile-row/unit offset.
  // Per-tile buffer offset ((x&7)<<12) becomes the ds_read IMMEDIATE.
  const char* adp[2][2];                // [K-half][unit]
  #pragma unroll
  for (int t = 0; t < 2; ++t)
    #pragma unroll
    for (int u = 0; u < 2; ++u)
      adp[t][u] = dbase + lm * 256 + ((((t << 3) | (kh << 1) | u) ^ lm) << 4);
  const float* cscl = cscw + lm;        // csc row base (index j*16 at use)

  f32x4 acc[4];
  #pragma unroll
  for (int mi = 0; mi < 4; ++mi)
    acc[mi] = f32x4{0.f, 0.f, 0.f, 0.f};
  const f32x4 fz = {0.f, 0.f, 0.f, 0.f};   // hoisted zero C-operand for MFMA t=0

  // Prologue wait: queue = {t0,t1, csc(2), afr(16), t2..t5}. vmcnt(4) leaves
  // the 4 newest (t2..t5) in flight; t0,t1 + csc + afr complete. lgkmcnt(0)
  // covers the csc LDS writes. Barrier publishes csc + staged chunks.
  asm volatile("s_waitcnt vmcnt(4) lgkmcnt(0)" ::: "memory");
  __builtin_amdgcn_s_barrier();
  __builtin_amdgcn_sched_barrier(0);

// One j-tile: ds_read b128 x4 (immediate buffer offset) -> MFMA x8 ->
// mul/exp/acc. No fences inside a window.
#define TILE(x_) do{                                                            \
    const int j_ = (x_) + ((x_) >= ib ? 1 : 0);                                 \
    i32x8 b_[2];                                                                \
    {                                                                           \
      i32x4 lo0 = *(const i32x4*)(adp[0][0] + (((x_) & 7) << 12));              \
      i32x4 hi0 = *(const i32x4*)(adp[0][1] + (((x_) & 7) << 12));              \
      i32x4 lo1 = *(const i32x4*)(adp[1][0] + (((x_) & 7) << 12));              \
      i32x4 hi1 = *(const i32x4*)(adp[1][1] + (((x_) & 7) << 12));              \
      b_[0] = i32x8{lo0.x, lo0.y, lo0.z, lo0.w, hi0.x, hi0.y, hi0.z, hi0.w};    \
      b_[1] = i32x8{lo1.x, lo1.y, lo1.z, lo1.w, hi1.x, hi1.y, hi1.z, hi1.w};    \
    }                                                                           \
    const float csc_ = cscl[j_ * 16];                                           \
    f32x4 S_[4];                                                                \
    _Pragma("unroll")                                                           \
    for (int mi_ = 0; mi_ < 4; ++mi_)                                           \
      S_[mi_] = __builtin_amdgcn_mfma_scale_f32_16x16x128_f8f6f4(afr[mi_][0], b_[0], fz, 0, 0, 0, 127, 0, 127); \
    _Pragma("unroll")                                                           \
    for (int mi_ = 0; mi_ < 4; ++mi_)                                           \
      S_[mi_] = __builtin_amdgcn_mfma_scale_f32_16x16x128_f8f6f4(afr[mi_][1], b_[1], S_[mi_], 0, 0, 0, 127, 0, 127); \
    _Pragma("unroll")                                                           \
    for (int mi_ = 0; mi_ < 4; ++mi_){                                          \
      const f32x4 t_ = S_[mi_] * csc_;                                          \
      f32x4 e_;                                                                 \
      _Pragma("unroll")                                                         \
      for (int r_ = 0; r_ < 4; ++r_) e_[r_] = __builtin_amdgcn_exp2f(t_[r_]);   \
      acc[mi_] += e_;                                                           \
    }                                                                           \
  }while(0)

  // Windows w=0..11 (FULLY UNROLLED -> compile-time x): tiles (2w,2w+1);
  // issue (2w+6,2w+7); end vmcnt(4) -> {2w+2,2w+3} landed (next window's
  // reads), 4 newest stay in flight across the barrier.
  #pragma unroll
  for (int wd = 0; wd < 12; ++wd){
    issue(2 * wd + 6);
    issue(2 * wd + 7);
    TILE(2 * wd);
    TILE(2 * wd + 1);
    asm volatile("s_waitcnt vmcnt(4)" ::: "memory");
    __builtin_amdgcn_s_barrier();
    __builtin_amdgcn_sched_barrier(0);
  }
  // w=12: tiles (24,25); issue t30; outstanding {26..30}; vmcnt(3) -> 26,27.
  issue(30);
  TILE(24);
  TILE(25);
  asm volatile("s_waitcnt vmcnt(3)" ::: "memory");
  __builtin_amdgcn_s_barrier();
  __builtin_amdgcn_sched_barrier(0);
  // w=13: tiles (26,27); vmcnt(1) -> 28,29 landed (t30 in flight).
  TILE(26);
  TILE(27);
  asm volatile("s_waitcnt vmcnt(1)" ::: "memory");
  __builtin_amdgcn_s_barrier();
  __builtin_amdgcn_sched_barrier(0);
  // w=14: tiles (28,29); vmcnt(0) -> t30 landed.
  TILE(28);
  TILE(29);
  asm volatile("s_waitcnt vmcnt(0)" ::: "memory");
  __builtin_amdgcn_s_barrier();
  __builtin_amdgcn_sched_barrier(0);
  TILE(30);

#undef TILE

  // Epilogue: per-dir log1p into LDS (aliases staging -- dead now), combine
  // dirs, coalesced store. C/D layout: col = lane&15, row = (lane>>4)*4+reg.
  __syncthreads();
  float* ebuf = (float*)smem;
  #pragma unroll
  for (int mi = 0; mi < 4; ++mi){
    #pragma unroll
    for (int r = 0; r < 4; ++r){
      const int m = sub * 64 + mi * 16 + (kh << 2) + r;
      ebuf[(dir * 256 + m) * 20 + lm] = __logf(1.f + acc[mi][r]);
    }
  }
  __syncthreads();
  #pragma unroll
  for (int p = 0; p < 2; ++p){
    const int i   = tid + p * 512;     // 0..1023 (float4 units of the 256x16 tile)
    const int row = i >> 2;
    const int c4  = i & 3;
    const f32x4 e0 = *(const f32x4*)(&ebuf[row * 20 + c4 * 4]);
    const f32x4 e1 = *(const f32x4*)(&ebuf[(256 + row) * 20 + c4 * 4]);
    f32x4 o;
    #pragma unroll
    for (int e = 0; e < 4; ++e) o[e] = -(e0[e] + e1[e]);
    *(f32x4*)(&out[(size_t)(r0 + row) * 256 + s0 + c4 * 4]) = o;
  }
}

extern "C" void kernel_launch(void* const* d_in, const int* in_sizes, int n_in,
                              void* d_out, int out_size, void* d_ws, size_t ws_size,
                              hipStream_t stream){
  const float* V = (const float*)d_in[2];   // back_VF  (pre_VF/pre_AF unused by reference)
  const float* A = (const float*)d_in[3];   // back_AF
  float* out = (float*)d_out;
  float* ivn = (float*)((char*)d_ws + IVN_OFF);
  float* icn = (float*)((char*)d_ws + ICN_OFF);
  float* csq = (float*)((char*)d_ws + CSQ_OFF);
  unsigned char* mats = (unsigned char*)((char*)d_ws + MATS_OFF);

  cast_ns_k<<<dim3(8, 32, 2), 256, 0, stream>>>(V, A, mats, csq);
  nreduce_k<<<dim3(32, 2), 256, 0, stream>>>(csq, ivn, icn);
  gemm_both_k<<<dim3(16, 32), 512, 0, stream>>>(mats, ivn, icn, out);
}

// Round 15
// 114.608 us; speedup vs baseline: 1.0191x; 1.0191x over previous
//
#include <hip/hip_runtime.h>
#include <cstdint>

// ============================================================================
// FINAL (v28 == v22, the session's best-measured kernel: harness 115.3 us,
// gemm_both_k ~42.5 us).
//
// Session summary (15 variants, R0-R13): every structural family mapped --
// {1,2,4} waves/SIMD x {fat,thin} waves x {private,shared} staging x
// {1,2,4}-tile sync windows x {drained,counted} vmcnt x {fenced,free}
// interiors x addressing micro-opts. All non-spilling cells land at
// 42.5-53 us; minimum here. Spill detector (WRITE_SIZE) caught 3 variants
// exceeding the 128-reg budget of 4 waves/SIMD (v15/v23/v24).
//
// Why 42.5 us is the plain-HIP plateau for this shape: per SIMD tile-
// position, MFMA ~1104 cy + VALU/trans ~1330 cy (fused exp: 16 trans-rate
// exp2 + 32 mul/add per wave-tile) + LDS ~800 cy; measured wall 3330 cy ~=
// the SUM (pipes phase-lockstep, not overlapped). Breaking lockstep needs
// pipeline registers that do not fit: live set (afr 64 + b 32 + S 16 +
// acc 16 + addr) == the 128-reg cap at 4 waves/SIMD; adding state spills,
// thinning waves loses more TLP/LDS-ratio than it buys. MFMA-only floor
// would be 14.3 us (MX-fp8 ubench 4661 TF); perfect-overlap bound ~20-24 us;
// neither reachable from HIP source at this register wall.
// ============================================================================
// Problem constants: B=32, T=D=256, rows R = B*T = 8192, K = 256.
#define R_TOT 8192
#define KD    256
#define SLOT  ((size_t)R_TOT * KD)            // bytes per fp8 image (2,097,152)
// ws layout (bytes):  total ~4.8 MB
#define IVN_OFF  0                            // 64 f32: 1/frobenius-norm [ten][j]
#define ICN_OFF  256                          // 2*8192 f32: 1/col-norm [ten][j][s]
#define CSQ_OFF  (ICN_OFF + 65536)            // 8 tc-partials x 2*8192 f32 = 512 KB
#define MATS_OFF (CSQ_OFF + 524288)           // 2 fp8 images (Vq, Aq), swizzled, 4 MB

typedef float f32x4 __attribute__((ext_vector_type(4)));
typedef int   i32x4 __attribute__((ext_vector_type(4)));
typedef int   i32x8 __attribute__((ext_vector_type(8)));   // 32 fp8 = one MX MFMA operand

__device__ __forceinline__ void glds16(const void* g, void* l){
  __builtin_amdgcn_global_load_lds((const __attribute__((address_space(1))) uint32_t*)g,
                                   (__attribute__((address_space(3))) uint32_t*)l, 16, 0, 0);
}

// Image layout: plain k-order rows (256 B per image row r), 16B chunk c
// stored at 16B slot c ^ (r & 15). XOR swizzle keeps MFMA-layout
// ds_read_b128 conflict-free (verified R7-R11, 65k conflicts = epilogue).
__global__ void cast_ns_k(const float* __restrict__ V, const float* __restrict__ A,
                          unsigned char* __restrict__ mats, float* __restrict__ csq){
  const int tc = blockIdx.x, j = blockIdx.y, ten = blockIdx.z;
  const int tid = threadIdx.x;
  const int g    = tid & 31;                 // d-chunk of 8 floats = 8 fp8 bytes
  const int tsub = tid >> 5;                 // 0..7
  const int c    = g >> 1;                   // 16B chunk index 0..15
  const int half = g & 1;                    // which 8B half of the chunk
  const float* X = (ten ? A : V) + (size_t)j * 65536;
  unsigned char* M = mats + (size_t)ten * SLOT + (size_t)j * 65536;
  float cs[8];
  #pragma unroll
  for (int e = 0; e < 8; ++e) cs[e] = 0.f;
  #pragma unroll
  for (int tt = 0; tt < 4; ++tt){
    const int t = tc * 32 + tt * 8 + tsub;
    const float4 p0 = *(const float4*)(X + t * 256 + g * 8);
    const float4 p1 = *(const float4*)(X + t * 256 + g * 8 + 4);
    cs[0] += p0.x * p0.x; cs[1] += p0.y * p0.y; cs[2] += p0.z * p0.z; cs[3] += p0.w * p0.w;
    cs[4] += p1.x * p1.x; cs[5] += p1.y * p1.y; cs[6] += p1.z * p1.z; cs[7] += p1.w * p1.w;
    int d0 = __builtin_amdgcn_cvt_pk_fp8_f32(p0.x, p0.y, 0, false);
    d0     = __builtin_amdgcn_cvt_pk_fp8_f32(p0.z, p0.w, d0, true);
    int d1 = __builtin_amdgcn_cvt_pk_fp8_f32(p1.x, p1.y, 0, false);
    d1     = __builtin_amdgcn_cvt_pk_fp8_f32(p1.z, p1.w, d1, true);
    int2 o; o.x = d0; o.y = d1;
    *(int2*)(M + (size_t)t * 256 + (((c ^ (t & 15)) << 4) | (half << 3))) = o;
  }
  __shared__ float red[8][256];
  #pragma unroll
  for (int e = 0; e < 8; ++e) red[tsub][g * 8 + e] = cs[e];
  __syncthreads();
  float s = 0.f;
  #pragma unroll
  for (int gg = 0; gg < 8; ++gg) s += red[gg][tid];
  csq[(size_t)((tc * 2 + ten) * 32 + j) * 256 + tid] = s;
}

// Finish norms: sum 8 tc-partials; icn = rsqrt, ivn = rsqrt of row-sum. Grid (32, 2).
__global__ void nreduce_k(const float* __restrict__ csq, float* __restrict__ ivn,
                          float* __restrict__ icn){
  const int j = blockIdx.x, ten = blockIdx.y, s = threadIdx.x;
  float c = 0.f;
  #pragma unroll
  for (int tc = 0; tc < 8; ++tc)
    c += csq[(size_t)((tc * 2 + ten) * 32 + j) * 256 + s];
  icn[ten * 8192 + j * 256 + s] = rsqrtf(c + 1e-18f);
  __shared__ float red[256];
  red[s] = c; __syncthreads();
  for (int off = 128; off > 0; off >>= 1){
    if (s < off) red[s] += red[s + off];
    __syncthreads();
  }
  if (s == 0) ivn[ten * 32 + j] = rsqrtf(red[0] + 1e-18f);
}

// Geometry (the winning cell): fat waves + block-shared staging + full TLP.
// Block = 512 thr = 2 dirs x 4 waves x 64 rows = one batch i x 16 cols
// (uniform diagonal skip + sivn). Grid 16x32 = 512 = 2 independent
// blocks/CU (phase stagger), 16 waves/CU = 4/SIMD. Wave live set ~128 regs
// = exactly the (512,4) budget; VGPR_Count reports 64 (arch half; acc side
// excluded -- never size launch bounds off it). Staged bytes = 512 x 31 x
// 8KB = 127 MB (4x cut vs private staging). Each wave stages 1KB (one
// glds16)/step, depth-2 prefetch, invariant-exact vmcnt(1), raw s_barrier
// (never vmcnt(0) mid-loop). LDS-read per MFMA = v13's proven 0.5KB ratio.
__global__ __launch_bounds__(512, 4) void gemm_both_k(const unsigned char* __restrict__ mats,
                                                      const float* __restrict__ ivn,
                                                      const float* __restrict__ icn,
                                                      float* __restrict__ out){
  // [0,32K): 2 dirs x 4 bufs x 4KB staging; [32K,36K): csc[2][32][16] f32.
  // Epilogue ebuf f32[2][256][20] = 40960 B aliases everything (post-loop).
  __shared__ __align__(16) char smem[40960];
  const int tid  = threadIdx.x;
  const int lane = tid & 63;
  const int w    = tid >> 6;            // 0..7
  const int dir  = w >> 2;              // waves 0-3 -> dir0; 4-7 -> dir1
  const int sub  = w & 3;               // row-64-group AND staging-chunk index
  const int lm   = lane & 15;
  const int kh   = lane >> 4;           // 0..3 (k-quad per K-half)
  const int s0   = blockIdx.x * 16;     // 16-col tile
  const int rb   = blockIdx.y;          // row-block == batch index i
  const int r0   = rb * 256;
  const int ib   = rb;                  // excluded diagonal j == i

  // dir0: rows Vq (scale 1/|V_i|F), cols Aq (scale 1/colnorm A); dir1 swapped.
  const unsigned char* rowmat = mats + (size_t)dir * SLOT;
  const unsigned char* colmat = mats + (size_t)(1 - dir) * SLOT;
  const float sivn = ivn[dir * 32 + ib] * 1.44269504088896340736f;  // * log2(e)

  char*  dbase = smem + dir * 16384;                  // this dir's 4 x 4KB bufs
  float* cscw  = (float*)(smem + 32768) + dir * 512;  // this dir's csc[32][16]
  const unsigned char* colbase = colmat + (size_t)s0 * 256;  // 4KB j-tile @ +j*65536
  const int lo16 = lane * 16;

  // Stage this wave's 1KB chunk of the dir's 4KB tile for col-tile x.
  auto issue = [&](int x){
    const int j = x + (x >= ib ? 1 : 0);
    glds16(colbase + (size_t)j * 65536 + sub * 1024 + lo16,
           dbase + ((x & 3) << 12) + sub * 1024 + lo16);
  };

  issue(0);
  issue(1);

  // Block-shared csc table (per dir): csc[j][col] = sivn * icn_col[j*256+s0+col].
  {
    const float* ib2 = icn + (size_t)(1 - dir) * 8192 + s0 + lm;
    #pragma unroll
    for (int jx = 0; jx < 2; ++jx){
      const int j = sub * 8 + jx * 4 + kh;
      cscw[j * 16 + lm] = sivn * ib2[j * 256];
    }
  }

  // A-fragments: this wave's 64 rows (group sub of the 256-row block);
  // K-half t, 16B unit u at slot (t*8 + kh*2 + u) ^ lm. 64 regs, invariant.
  i32x8 afr[4][2];                      // [mi][K-half]
  #pragma unroll
  for (int mi = 0; mi < 4; ++mi){
    const unsigned char* rp = rowmat + (size_t)(r0 + sub * 64 + mi * 16 + lm) * 256;
    #pragma unroll
    for (int t = 0; t < 2; ++t){
      i32x4 lo = *(const i32x4*)(rp + ((((t << 3) | (kh << 1) | 0) ^ lm) << 4));
      i32x4 hi = *(const i32x4*)(rp + ((((t << 3) | (kh << 1) | 1) ^ lm) << 4));
      afr[mi][t] = i32x8{lo.x, lo.y, lo.z, lo.w, hi.x, hi.y, hi.z, hi.w};
    }
  }
  #pragma unroll
  for (int mi = 0; mi < 4; ++mi)
    #pragma unroll
    for (int t = 0; t < 2; ++t)
      asm volatile("" : "+v"(afr[mi][t]));

  // ds_read offsets: tile row lm (16 rows = 16 cols of sim), K-half t, unit
  // u; (row&15)==lm so the XOR key matches staging (s0 multiple of 16).
  int ad[2][2];                         // [K-half][unit]
  #pragma unroll
  for (int t = 0; t < 2; ++t)
    #pragma unroll
    for (int u = 0; u < 2; ++u)
      ad[t][u] = lm * 256 + ((((t << 3) | (kh << 1) | u) ^ lm) << 4);

  f32x4 acc[4];
  #pragma unroll
  for (int mi = 0; mi < 4; ++mi)
    acc[mi] = f32x4{0.f, 0.f, 0.f, 0.f};
  const f32x4 fz = {0.f, 0.f, 0.f, 0.f};   // hoisted zero C-operand for MFMA t=0

  // Drain prologue (csc gloads + afr + DMA(0),DMA(1) + csc LDS writes), sync.
  asm volatile("s_waitcnt vmcnt(0) lgkmcnt(0)" ::: "memory");
  __builtin_amdgcn_s_barrier();
  __builtin_amdgcn_sched_barrier(0);

  // vmcnt invariant at step-x start: outstanding = {x+1} (per wave).
  #pragma unroll 1
  for (int x = 0; x < 31; ++x){
    const int j = x + (x >= ib ? 1 : 0);

    if (x <= 28) issue(x + 2);          // -> outstanding {x+1, x+2}

    const char* rbuf = dbase + ((x & 3) << 12);
    i32x8 b[2];                         // [K-half]
    #pragma unroll
    for (int t = 0; t < 2; ++t){
      i32x4 lo = *(const i32x4*)(rbuf + ad[t][0]);
      i32x4 hi = *(const i32x4*)(rbuf + ad[t][1]);
      b[t] = i32x8{lo.x, lo.y, lo.z, lo.w, hi.x, hi.y, hi.z, hi.w};
    }
    const float csc = cscw[j * 16 + lm];

    f32x4 S[4];
    #pragma unroll
    for (int mi = 0; mi < 4; ++mi)
      S[mi] = __builtin_amdgcn_mfma_scale_f32_16x16x128_f8f6f4(afr[mi][0], b[0], fz, 0, 0, 0, 127, 0, 127);
    #pragma unroll
    for (int mi = 0; mi < 4; ++mi)
      S[mi] = __builtin_amdgcn_mfma_scale_f32_16x16x128_f8f6f4(afr[mi][1], b[1], S[mi], 0, 0, 0, 127, 0, 127);

    #pragma unroll
    for (int mi = 0; mi < 4; ++mi){
      const f32x4 t0 = S[mi] * csc;
      f32x4 e0;
      #pragma unroll
      for (int r = 0; r < 4; ++r) e0[r] = __builtin_amdgcn_exp2f(t0[r]);
      acc[mi] += e0;
    }

    // End-of-step: ensure DMA(x+1) landed (x+2 stays in flight -> vmcnt(1)),
    // then raw barrier so all 8 waves' chunks are visible.
    if (x <= 28)      asm volatile("s_waitcnt vmcnt(1)" ::: "memory");
    else if (x == 29) asm volatile("s_waitcnt vmcnt(0)" ::: "memory");
    if (x < 30){
      __builtin_amdgcn_s_barrier();
      __builtin_amdgcn_sched_barrier(0);
    }
  }

  // Epilogue: per-dir log1p into LDS (aliases staging -- dead now), combine
  // dirs, coalesced store. C/D layout: col = lane&15, row = (lane>>4)*4+reg.
  __syncthreads();
  float* ebuf = (float*)smem;
  #pragma unroll
  for (int mi = 0; mi < 4; ++mi){
    #pragma unroll
    for (int r = 0; r < 4; ++r){
      const int m = sub * 64 + mi * 16 + (kh << 2) + r;
      ebuf[(dir * 256 + m) * 20 + lm] = __logf(1.f + acc[mi][r]);
    }
  }
  __syncthreads();
  #pragma unroll
  for (int p = 0; p < 2; ++p){
    const int i   = tid + p * 512;     // 0..1023 (float4 units of the 256x16 tile)
    const int row = i >> 2;
    const int c4  = i & 3;
    const f32x4 e0 = *(const f32x4*)(&ebuf[row * 20 + c4 * 4]);
    const f32x4 e1 = *(const f32x4*)(&ebuf[(256 + row) * 20 + c4 * 4]);
    f32x4 o;
    #pragma unroll
    for (int e = 0; e < 4; ++e) o[e] = -(e0[e] + e1[e]);
    *(f32x4*)(&out[(size_t)(r0 + row) * 256 + s0 + c4 * 4]) = o;
  }
}

extern "C" void kernel_launch(void* const* d_in, const int* in_sizes, int n_in,
                              void* d_out, int out_size, void* d_ws, size_t ws_size,
                              hipStream_t stream){
  const float* V = (const float*)d_in[2];   // back_VF  (pre_VF/pre_AF unused by reference)
  const float* A = (const float*)d_in[3];   // back_AF
  float* out = (float*)d_out;
  float* ivn = (float*)((char*)d_ws + IVN_OFF);
  float* icn = (float*)((char*)d_ws + ICN_OFF);
  float* csq = (float*)((char*)d_ws + CSQ_OFF);
  unsigned char* mats = (unsigned char*)((char*)d_ws + MATS_OFF);

  cast_ns_k<<<dim3(8, 32, 2), 256, 0, stream>>>(V, A, mats, csq);
  nreduce_k<<<dim3(32, 2), 256, 0, stream>>>(csq, ivn, icn);
  gemm_both_k<<<dim3(16, 32), 512, 0, stream>>>(mats, ivn, icn, out);
}